// Round 6
// baseline (143.372 us; speedup 1.0000x reference)
//
#include <hip/hip_runtime.h>

// SelfAttention3D: B=4, C=128, N=16^3=4096, Cqk=16.
// R10: R9 structure + amdgpu_waves_per_eu(2,2) on the attn kernel.
// Evidence from R5/R8/R9: launch_bounds(512,2) leaves the allocator's
// occupancy TARGET at 4 waves/EU (128 regs) and it spills to hold that
// (R8/R9: 200MB scratch) instead of dropping to 2 waves/EU. R5 "fit" 124
// only by serializing V loads into PV (the exposed latency we measured).
// vf[16]+acc[16] alone = 128 regs, so the pipelined structure NEEDS the
// 256-reg tier -> pin waves/EU to exactly 2 with the clang attribute.
// Structure (unchanged from R9): per iter t:
//   read pa(qh0) from P[t&1] (written t-1) -> 16 V(t) loads (contiguous
//   16KB tile, uniform base) -> produce P(t+1) (QK+exp2+cvt_pk -> LDS
//   buf (t+1)&1) -> reload kf <- K(t+2) (regs dead after produce) ->
//   PV qh0 -> pa(qh1) -> PV qh1. No in-loop barriers.

typedef __attribute__((ext_vector_type(8))) short short8;
typedef __attribute__((ext_vector_type(4))) float f32x4;

#define NTOK 4096
#define CDIM 128
#define L2E 1.44269504088896340736f

__device__ __forceinline__ unsigned short f2bf(float f) {
  unsigned int u = __float_as_uint(f);
  return (unsigned short)((u + 0x7fffu + ((u >> 16) & 1u)) >> 16);
}

// ---------------------------------------------------------------------------
// Projection (unchanged from R8/R9, harness-verified): q,k,v channel-GEMMs.
// qb,kb: [B][N][16] row per token. Q pre-scaled by log2(e).
// vb tiled: elem(b,c,m) = b*524288 + (m>>6)*8192
//           + ((c>>4)*2 + ((m>>5)&1))*512 + ((m>>3)&3)*128 + (c&15)*8 + (m&7)
// ---------------------------------------------------------------------------
__global__ __launch_bounds__(256) void sa3d_proj(
    const float* __restrict__ x,
    const float* __restrict__ Wq, const float* __restrict__ bq,
    const float* __restrict__ Wk, const float* __restrict__ bk,
    const float* __restrict__ Wv, const float* __restrict__ bv,
    unsigned short* __restrict__ qb, unsigned short* __restrict__ kb,
    unsigned short* __restrict__ vb)
{
  __shared__ unsigned short Wl[160 * 136];
  __shared__ unsigned short xT[64 * 136];
  const int tid = threadIdx.x;
  const int b = (blockIdx.x & 7) >> 1;
  const int nt = ((blockIdx.x >> 3) << 1) | (blockIdx.x & 1);  // [0,64)
  const int n0 = nt << 6;

  for (int i = 0; i < 80; ++i) {
    int idx = i * 256 + tid;
    int o = idx >> 7, c = idx & 127;
    float wv;
    if (o < 16)      wv = Wq[o * 128 + c] * L2E;   // fold log2e into Q
    else if (o < 32) wv = Wk[(o - 16) * 128 + c];
    else             wv = Wv[(o - 32) * 128 + c];
    Wl[o * 136 + c] = f2bf(wv);
  }
  {
    int nn = tid & 63, cg = tid >> 6;
    const float* xp = x + (size_t)b * CDIM * NTOK + n0 + nn;
    for (int cp = 0; cp < 16; ++cp) {
      int c = cg * 32 + cp * 2;
      float v0 = xp[(size_t)c * NTOK];
      float v1 = xp[(size_t)(c + 1) * NTOK];
      *(unsigned int*)&xT[nn * 136 + c] =
          (unsigned int)f2bf(v0) | ((unsigned int)f2bf(v1) << 16);
    }
  }
  __syncthreads();

  const int w = tid >> 6, lane = tid & 63;
  const int l15 = lane & 15, g = lane >> 4;

  short8 bfr[4];
#pragma unroll
  for (int ks = 0; ks < 4; ++ks)
    bfr[ks] = *(const short8*)&xT[(w * 16 + l15) * 136 + ks * 32 + g * 8];

  const int n = n0 + w * 16 + l15;
#pragma unroll
  for (int ot = 0; ot < 10; ++ot) {
    f32x4 acc = {};
#pragma unroll
    for (int ks = 0; ks < 4; ++ks) {
      short8 af = *(const short8*)&Wl[(ot * 16 + l15) * 136 + ks * 32 + g * 8];
      acc = __builtin_amdgcn_mfma_f32_16x16x32_bf16(af, bfr[ks], acc, 0, 0, 0);
    }
    int ob = ot * 16 + 4 * g;
    if (ot == 0) {
      unsigned int p0 = (unsigned int)f2bf(acc[0] + bq[ob] * L2E) |
                        ((unsigned int)f2bf(acc[1] + bq[ob + 1] * L2E) << 16);
      unsigned int p1 = (unsigned int)f2bf(acc[2] + bq[ob + 2] * L2E) |
                        ((unsigned int)f2bf(acc[3] + bq[ob + 3] * L2E) << 16);
      unsigned int* d = (unsigned int*)&qb[((size_t)b * NTOK + n) * 16 + ob];
      d[0] = p0; d[1] = p1;
    } else if (ot == 1) {
      int o2 = ob - 16;
      unsigned int p0 = (unsigned int)f2bf(acc[0] + bk[o2]) |
                        ((unsigned int)f2bf(acc[1] + bk[o2 + 1]) << 16);
      unsigned int p1 = (unsigned int)f2bf(acc[2] + bk[o2 + 2]) |
                        ((unsigned int)f2bf(acc[3] + bk[o2 + 3]) << 16);
      unsigned int* d = (unsigned int*)&kb[((size_t)b * NTOK + n) * 16 + o2];
      d[0] = p0; d[1] = p1;
    } else {
#pragma unroll
      for (int r = 0; r < 4; ++r) {
        int o = ob + r - 32;  // channel c in [0,128)
        size_t eidx = (size_t)(n >> 6) * 8192 +
                      (size_t)((o >> 4) * 2 + ((n >> 5) & 1)) * 512 +
                      (size_t)((n >> 3) & 3) * 128 + (o & 15) * 8 + (n & 7);
        vb[(size_t)b * (CDIM * NTOK) + eidx] = f2bf(acc[r] + bv[o]);
      }
    }
  }
}

// ---------------------------------------------------------------------------
// Flash attention. 512 blocks x 512 threads (8 waves), no in-loop barriers.
// Block: batch b=(bid&7)>>1 (XCD-pinned), 32 queries; wave w owns keys
// [w*512,(w+1)*512) = 8 tiles of 64. Pinned to exactly 2 waves/EU so the
// allocator gets the 256-reg budget the pipelined live set (~180) needs.
// End: LDS tree-reduce of 8 waves' (acc,L), wave-0 epilogue gamma*acc/L + x.
// ---------------------------------------------------------------------------
__global__ __launch_bounds__(512)
__attribute__((amdgpu_waves_per_eu(2, 2)))
void sa3d_attn(
    const unsigned short* __restrict__ qb, const unsigned short* __restrict__ kb,
    const unsigned short* __restrict__ vb,
    const float* __restrict__ x, const float* __restrict__ gamma,
    float* __restrict__ out)
{
  // LDS: [0,73728): 8 waves x 2 P buffers x (32 rows x 72 shorts = 4608 B)
  //      after loop (reuse): [0,65536) 4 reduce slots; [65536,66560) L area
  __shared__ __align__(16) unsigned char smem[73728];

  const int tid = threadIdx.x;
  const int w = tid >> 6, lane = tid & 63;
  const int l15 = lane & 15, g = lane >> 4;
  const int b = (blockIdx.x & 7) >> 1;
  const int qt = ((blockIdx.x >> 3) << 1) | (blockIdx.x & 1);  // [0,128)
  const int q0 = qt << 5;

  unsigned short* PLw = (unsigned short*)(smem + w * 9216);  // 2 x 2304 shorts
  float* LDp = (float*)(smem + 65536);

  const unsigned short* qbase = qb + (size_t)b * NTOK * 16;
  const unsigned short* kbase = kb + (size_t)b * NTOK * 16;
  const unsigned short* vbase = vb + (size_t)b * CDIM * NTOK;

  short8 aq[2] = {short8{}, short8{}};
#pragma unroll
  for (int qh = 0; qh < 2; ++qh)
    if (g < 2)
      aq[qh] = *(const short8*)&qbase[(size_t)(q0 + qh * 16 + l15) * 16 + g * 8];

  f32x4 acc[16];  // [qh*8 + ct]
#pragma unroll
  for (int i = 0; i < 16; ++i) acc[i] = (f32x4){};
  float Lp[2][4] = {{0.f, 0.f, 0.f, 0.f}, {0.f, 0.f, 0.f, 0.f}};

  const int kv0 = w << 9;                       // 512 keys per wave
  const int voff = g * 128 + l15 * 8;           // lane offset inside V frag
  const unsigned short* vtile = vbase + (size_t)(kv0 >> 6) * 8192;

  short8 kf[4];  // single K buffer, reloaded after each produce

#define LOADK(TT)                                                             \
  {                                                                           \
    _Pragma("unroll") for (int kt = 0; kt < 4; ++kt) {                        \
      kf[kt] = short8{};                                                      \
      if (g < 2)                                                              \
        kf[kt] = *(const short8*)&kbase[                                      \
            (size_t)(kv0 + ((TT) << 6) + kt * 16 + l15) * 16 + g * 8];        \
    }                                                                         \
  }

  // Produce P(TN) into LDS buf TN&1 from kf: QK -> exp2 -> cvt_pk -> 4 b16.
#define SA_PRODUCE(TN)                                                        \
  {                                                                           \
    const int pbn = ((TN) & 1) * 2304;                                        \
    _Pragma("unroll") for (int kt = 0; kt < 4; ++kt) {                        \
      _Pragma("unroll") for (int qh = 0; qh < 2; ++qh) {                      \
        f32x4 z = {};                                                         \
        f32x4 s = __builtin_amdgcn_mfma_f32_16x16x32_bf16(aq[qh], kf[kt],     \
                                                          z, 0, 0, 0);        \
        float e0 = __builtin_exp2f(s[0]);                                     \
        float e1 = __builtin_exp2f(s[1]);                                     \
        float e2 = __builtin_exp2f(s[2]);                                     \
        float e3 = __builtin_exp2f(s[3]);                                     \
        Lp[qh][0] += e0; Lp[qh][1] += e1;                                     \
        Lp[qh][2] += e2; Lp[qh][3] += e3;                                     \
        unsigned int pk0, pk1;                                                \
        asm("v_cvt_pk_bf16_f32 %0, %1, %2" : "=v"(pk0) : "v"(e0), "v"(e1));   \
        asm("v_cvt_pk_bf16_f32 %0, %1, %2" : "=v"(pk1) : "v"(e2), "v"(e3));   \
        const int rb = pbn + (qh * 16 + 4 * g) * 72 + kt * 16 + l15;          \
        PLw[rb]       = (unsigned short)pk0;                                  \
        PLw[rb + 72]  = (unsigned short)(pk0 >> 16);                          \
        PLw[rb + 144] = (unsigned short)pk1;                                  \
        PLw[rb + 216] = (unsigned short)(pk1 >> 16);                          \
      }                                                                       \
    }                                                                         \
  }

  // Iter T: pa(qh0) -> V(T) -> produce P(T+1) (if PROD) -> kf<-K(T+2)
  // (if PREF) -> PV qh0 -> pa(qh1) -> PV qh1.
#define SA_ITER(T, PROD, PREF)                                                \
  {                                                                           \
    const int pbo = ((T) & 1) * 2304;                                         \
    short8 pa0[2];                                                            \
    _Pragma("unroll") for (int ch = 0; ch < 2; ++ch)                          \
      pa0[ch] = *(const short8*)&PLw[pbo + l15 * 72 + ch * 32 + g * 8];       \
    short8 vf[16];                                                            \
    {                                                                         \
      const unsigned short* vt = vtile + (size_t)(T) * 8192;                  \
      _Pragma("unroll") for (int f = 0; f < 16; ++f)                          \
        vf[f] = *(const short8*)&vt[f * 512 + voff];                          \
    }                                                                         \
    if (PROD) SA_PRODUCE((T) + 1);                                            \
    if (PREF) LOADK((T) + 2);                                                 \
    __builtin_amdgcn_s_setprio(1);                                            \
    _Pragma("unroll") for (int ch = 0; ch < 2; ++ch)                          \
      _Pragma("unroll") for (int ct = 0; ct < 8; ++ct)                        \
        acc[ct] = __builtin_amdgcn_mfma_f32_16x16x32_bf16(                    \
            pa0[ch], vf[ct * 2 + ch], acc[ct], 0, 0, 0);                      \
    __builtin_amdgcn_s_setprio(0);                                            \
    short8 pa1[2];                                                            \
    _Pragma("unroll") for (int ch = 0; ch < 2; ++ch)                          \
      pa1[ch] = *(const short8*)&PLw[pbo + (16 + l15) * 72 + ch * 32 + g * 8];\
    __builtin_amdgcn_s_setprio(1);                                            \
    _Pragma("unroll") for (int ch = 0; ch < 2; ++ch)                          \
      _Pragma("unroll") for (int ct = 0; ct < 8; ++ct)                        \
        acc[8 + ct] = __builtin_amdgcn_mfma_f32_16x16x32_bf16(                \
            pa1[ch], vf[ct * 2 + ch], acc[8 + ct], 0, 0, 0);                  \
    __builtin_amdgcn_s_setprio(0);                                            \
  }

  LOADK(0);
  SA_PRODUCE(0);
  LOADK(1);
  SA_ITER(0, 1, 1);
  SA_ITER(1, 1, 1);
  SA_ITER(2, 1, 1);
  SA_ITER(3, 1, 1);
  SA_ITER(4, 1, 1);
  SA_ITER(5, 1, 1);
  SA_ITER(6, 1, 0);
  SA_ITER(7, 0, 0);
#undef SA_PRODUCE
#undef SA_ITER
#undef LOADK

  // intra-wave L reduce over the 16 key-columns
#pragma unroll
  for (int qh = 0; qh < 2; ++qh)
#pragma unroll
    for (int r = 0; r < 4; ++r) {
      float v = Lp[qh][r];
      v += __shfl_xor(v, 1);
      v += __shfl_xor(v, 2);
      v += __shfl_xor(v, 4);
      v += __shfl_xor(v, 8);
      Lp[qh][r] = v;
    }

  // cross-wave tree reduce: 8 -> 4 -> 2 -> 1 (XOR-swizzled 256B rows)
  const int rowb = lane * 256;
  const int sw = (l15) << 4;

#define ACC_STORE(i)                                                        \
  {                                                                         \
    char* base = (char*)smem + (i) * 16384 + rowb;                          \
    _Pragma("unroll") for (int j = 0; j < 16; ++j)                          \
        *(f32x4*)(base + ((j * 16) ^ sw)) = acc[j];                         \
    if (l15 == 0) {                                                         \
      _Pragma("unroll") for (int qh = 0; qh < 2; ++qh)                      \
          _Pragma("unroll") for (int r = 0; r < 4; ++r)                     \
              LDp[(i) * 32 + qh * 16 + 4 * g + r] = Lp[qh][r];              \
    }                                                                       \
  }
#define ACC_ADD(i)                                                          \
  {                                                                         \
    char* base = (char*)smem + (i) * 16384 + rowb;                          \
    _Pragma("unroll") for (int j = 0; j < 16; ++j)                          \
        acc[j] += *(const f32x4*)(base + ((j * 16) ^ sw));                  \
    _Pragma("unroll") for (int qh = 0; qh < 2; ++qh)                        \
        _Pragma("unroll") for (int r = 0; r < 4; ++r)                       \
            Lp[qh][r] += LDp[(i) * 32 + qh * 16 + 4 * g + r];               \
  }

  __syncthreads();
  if (w >= 4) ACC_STORE(w - 4);
  __syncthreads();
  if (w < 4) ACC_ADD(w);
  __syncthreads();
  if (w == 2 || w == 3) ACC_STORE(w - 2);
  __syncthreads();
  if (w < 2) ACC_ADD(w);
  __syncthreads();
  if (w == 1) ACC_STORE(0);
  __syncthreads();

  if (w == 0) {
    ACC_ADD(0);
    const float ga = gamma[0];
    float inv[2][4];
#pragma unroll
    for (int qh = 0; qh < 2; ++qh)
#pragma unroll
      for (int r = 0; r < 4; ++r) inv[qh][r] = 1.0f / Lp[qh][r];

    const float* xb = x + (size_t)b * CDIM * NTOK;
    float* ob = out + (size_t)b * CDIM * NTOK;
#pragma unroll
    for (int qh = 0; qh < 2; ++qh)
#pragma unroll
      for (int ct = 0; ct < 8; ++ct) {
        int c = ct * 16 + l15;
        size_t idx = (size_t)c * NTOK + q0 + qh * 16 + 4 * g;
        f32x4 xv = *(const f32x4*)&xb[idx];
        f32x4 o;
#pragma unroll
        for (int r = 0; r < 4; ++r)
          o[r] = ga * acc[qh * 8 + ct][r] * inv[qh][r] + xv[r];
        *(f32x4*)&ob[idx] = o;
      }
  }
}

extern "C" void kernel_launch(void* const* d_in, const int* in_sizes, int n_in,
                              void* d_out, int out_size, void* d_ws, size_t ws_size,
                              hipStream_t stream) {
  const float* x     = (const float*)d_in[0];
  const float* Wq    = (const float*)d_in[1];
  const float* bq    = (const float*)d_in[2];
  const float* Wk    = (const float*)d_in[3];
  const float* bk    = (const float*)d_in[4];
  const float* Wv    = (const float*)d_in[5];
  const float* bv    = (const float*)d_in[6];
  const float* gamma = (const float*)d_in[7];

  unsigned short* qb = (unsigned short*)d_ws;          // 512 KB
  unsigned short* kb = qb + (size_t)4 * NTOK * 16;     // 512 KB
  unsigned short* vb = kb + (size_t)4 * NTOK * 16;     // 4 MB (tiled layout)
  float* outp = (float*)d_out;

  sa3d_proj<<<dim3(256), dim3(256), 0, stream>>>(x, Wq, bq, Wk, bk, Wv, bv,
                                                 qb, kb, vb);
  sa3d_attn<<<dim3(512), dim3(512), 0, stream>>>(qb, kb, vb, x, gamma, outp);
}

// Round 7
// 103.593 us; speedup vs baseline: 1.3840x; 1.3840x over previous
//
#include <hip/hip_runtime.h>

// SelfAttention3D: B=4, C=128, N=16^3=4096, Cqk=16.
// R11: R5's proven no-spill skeleton (512 blocks x 8 waves, 32q/block,
// 512 keys/wave, same-iter LDS P, vf[16] reg-staged V, K ping-pong,
// launch_bounds(512,2) -> 124 VGPR) + the three zero-register VALU/latency
// improvements harness-verified in R8-R10:
//  - contiguous 16KB V tiles: vt + f*512 + voff, uniform base (addr VALU ~0)
//  - exp2 with log2(e) folded into Wq/bq in proj (-32 vmul/iter)
//  - v_cvt_pk_bf16_f32 P packing (-~96 VALU/iter)
// plus split pa0/pa1 reads (transient peak -8 regs) and setprio around PV.
// Allocator lesson (R6-R10): the attn kernel is pinned to the 128-reg tier;
// amdgpu_waves_per_eu is inert; structures must fit ~124 live regs.

typedef __attribute__((ext_vector_type(8))) short short8;
typedef __attribute__((ext_vector_type(4))) float f32x4;

#define NTOK 4096
#define CDIM 128
#define L2E 1.44269504088896340736f

__device__ __forceinline__ unsigned short f2bf(float f) {
  unsigned int u = __float_as_uint(f);
  return (unsigned short)((u + 0x7fffu + ((u >> 16) & 1u)) >> 16);
}

// ---------------------------------------------------------------------------
// Projection (R8 version, harness-verified): q,k,v channel-GEMMs.
// qb,kb: [B][N][16] row per token. Q pre-scaled by log2(e).
// vb tiled: elem(b,c,m) = b*524288 + (m>>6)*8192
//           + ((c>>4)*2 + ((m>>5)&1))*512 + ((m>>3)&3)*128 + (c&15)*8 + (m&7)
// ---------------------------------------------------------------------------
__global__ __launch_bounds__(256) void sa3d_proj(
    const float* __restrict__ x,
    const float* __restrict__ Wq, const float* __restrict__ bq,
    const float* __restrict__ Wk, const float* __restrict__ bk,
    const float* __restrict__ Wv, const float* __restrict__ bv,
    unsigned short* __restrict__ qb, unsigned short* __restrict__ kb,
    unsigned short* __restrict__ vb)
{
  __shared__ unsigned short Wl[160 * 136];
  __shared__ unsigned short xT[64 * 136];
  const int tid = threadIdx.x;
  const int b = (blockIdx.x & 7) >> 1;
  const int nt = ((blockIdx.x >> 3) << 1) | (blockIdx.x & 1);  // [0,64)
  const int n0 = nt << 6;

  for (int i = 0; i < 80; ++i) {
    int idx = i * 256 + tid;
    int o = idx >> 7, c = idx & 127;
    float wv;
    if (o < 16)      wv = Wq[o * 128 + c] * L2E;   // fold log2e into Q
    else if (o < 32) wv = Wk[(o - 16) * 128 + c];
    else             wv = Wv[(o - 32) * 128 + c];
    Wl[o * 136 + c] = f2bf(wv);
  }
  {
    int nn = tid & 63, cg = tid >> 6;
    const float* xp = x + (size_t)b * CDIM * NTOK + n0 + nn;
    for (int cp = 0; cp < 16; ++cp) {
      int c = cg * 32 + cp * 2;
      float v0 = xp[(size_t)c * NTOK];
      float v1 = xp[(size_t)(c + 1) * NTOK];
      *(unsigned int*)&xT[nn * 136 + c] =
          (unsigned int)f2bf(v0) | ((unsigned int)f2bf(v1) << 16);
    }
  }
  __syncthreads();

  const int w = tid >> 6, lane = tid & 63;
  const int l15 = lane & 15, g = lane >> 4;

  short8 bfr[4];
#pragma unroll
  for (int ks = 0; ks < 4; ++ks)
    bfr[ks] = *(const short8*)&xT[(w * 16 + l15) * 136 + ks * 32 + g * 8];

  const int n = n0 + w * 16 + l15;
#pragma unroll
  for (int ot = 0; ot < 10; ++ot) {
    f32x4 acc = {};
#pragma unroll
    for (int ks = 0; ks < 4; ++ks) {
      short8 af = *(const short8*)&Wl[(ot * 16 + l15) * 136 + ks * 32 + g * 8];
      acc = __builtin_amdgcn_mfma_f32_16x16x32_bf16(af, bfr[ks], acc, 0, 0, 0);
    }
    int ob = ot * 16 + 4 * g;
    if (ot == 0) {
      unsigned int p0 = (unsigned int)f2bf(acc[0] + bq[ob] * L2E) |
                        ((unsigned int)f2bf(acc[1] + bq[ob + 1] * L2E) << 16);
      unsigned int p1 = (unsigned int)f2bf(acc[2] + bq[ob + 2] * L2E) |
                        ((unsigned int)f2bf(acc[3] + bq[ob + 3] * L2E) << 16);
      unsigned int* d = (unsigned int*)&qb[((size_t)b * NTOK + n) * 16 + ob];
      d[0] = p0; d[1] = p1;
    } else if (ot == 1) {
      int o2 = ob - 16;
      unsigned int p0 = (unsigned int)f2bf(acc[0] + bk[o2]) |
                        ((unsigned int)f2bf(acc[1] + bk[o2 + 1]) << 16);
      unsigned int p1 = (unsigned int)f2bf(acc[2] + bk[o2 + 2]) |
                        ((unsigned int)f2bf(acc[3] + bk[o2 + 3]) << 16);
      unsigned int* d = (unsigned int*)&kb[((size_t)b * NTOK + n) * 16 + o2];
      d[0] = p0; d[1] = p1;
    } else {
#pragma unroll
      for (int r = 0; r < 4; ++r) {
        int o = ob + r - 32;  // channel c in [0,128)
        size_t eidx = (size_t)(n >> 6) * 8192 +
                      (size_t)((o >> 4) * 2 + ((n >> 5) & 1)) * 512 +
                      (size_t)((n >> 3) & 3) * 128 + (o & 15) * 8 + (n & 7);
        vb[(size_t)b * (CDIM * NTOK) + eidx] = f2bf(acc[r] + bv[o]);
      }
    }
  }
}

// ---------------------------------------------------------------------------
// Flash attention. 512 blocks x 512 threads (8 waves), no in-loop barriers.
// Block: batch b=(bid&7)>>1 (XCD-pinned), 32 queries; wave w owns keys
// [w*512,(w+1)*512) = 8 tiles of 64. Per iter T (R5 skeleton):
//   16 V(T) loads (contiguous tile, uniform base) ->
//   produce P(T): QK MFMA + exp2 + cvt_pk -> per-wave LDS P ->
//   K(T+1) prefetch into the other ping-pong buffer ->
//   pa0 read -> PV qh0 -> pa1 read -> PV qh1 (setprio around MFMA).
// End: LDS tree-reduce of 8 waves' (acc,L), wave-0 epilogue gamma*acc/L + x.
// ---------------------------------------------------------------------------
__global__ __launch_bounds__(512, 2) void sa3d_attn(
    const unsigned short* __restrict__ qb, const unsigned short* __restrict__ kb,
    const unsigned short* __restrict__ vb,
    const float* __restrict__ x, const float* __restrict__ gamma,
    float* __restrict__ out)
{
  // LDS: [0,36864): 8 per-wave P buffers (32 rows x 72 shorts = 4608 B each)
  //      [0,65536): 4 reduce slots of 16 KB (reused after loop)
  //      [65536,66560): L reduce area, 4 slots x 32 floats
  __shared__ __align__(16) unsigned char smem[66560];

  const int tid = threadIdx.x;
  const int w = tid >> 6, lane = tid & 63;
  const int l15 = lane & 15, g = lane >> 4;
  const int b = (blockIdx.x & 7) >> 1;
  const int qt = ((blockIdx.x >> 3) << 1) | (blockIdx.x & 1);  // [0,128)
  const int q0 = qt << 5;

  unsigned short* PLw = (unsigned short*)smem + w * 2304;  // 32 x 72 shorts
  float* LDp = (float*)(smem + 65536);

  const unsigned short* qbase = qb + (size_t)b * NTOK * 16;
  const unsigned short* kbase = kb + (size_t)b * NTOK * 16;
  const unsigned short* vbase = vb + (size_t)b * CDIM * NTOK;

  short8 aq[2] = {short8{}, short8{}};
#pragma unroll
  for (int qh = 0; qh < 2; ++qh)
    if (g < 2)
      aq[qh] = *(const short8*)&qbase[(size_t)(q0 + qh * 16 + l15) * 16 + g * 8];

  f32x4 acc[16];  // [qh*8 + ct]
#pragma unroll
  for (int i = 0; i < 16; ++i) acc[i] = (f32x4){};
  float Lp[2][4] = {{0.f, 0.f, 0.f, 0.f}, {0.f, 0.f, 0.f, 0.f}};

  const int kv0 = w << 9;                       // 512 keys per wave
  const int voff = g * 128 + l15 * 8;           // lane offset inside V frag
  const unsigned short* vtile = vbase + (size_t)(kv0 >> 6) * 8192;

  // K prefetch for tile 0
  short8 kfa[4], kfb[4];
#pragma unroll
  for (int kt = 0; kt < 4; ++kt) {
    kfa[kt] = short8{};
    if (g < 2)
      kfa[kt] = *(const short8*)&kbase[(size_t)(kv0 + kt * 16 + l15) * 16 + g * 8];
  }

  // One KV-tile iteration: V reg-stage -> produce P (QK+exp2+cvt_pk) ->
  // K prefetch -> pa0 -> PV qh0 -> pa1 -> PV qh1.
#define SA_ITER(T, KC, KN)                                                    \
  {                                                                           \
    short8 vf[16];                                                            \
    {                                                                         \
      const unsigned short* vt = vtile + (size_t)(T) * 8192;                  \
      _Pragma("unroll") for (int f = 0; f < 16; ++f)                          \
        vf[f] = *(const short8*)&vt[f * 512 + voff];                          \
    }                                                                         \
    _Pragma("unroll") for (int kt = 0; kt < 4; ++kt) {                        \
      _Pragma("unroll") for (int qh = 0; qh < 2; ++qh) {                      \
        f32x4 z = {};                                                         \
        f32x4 s = __builtin_amdgcn_mfma_f32_16x16x32_bf16(aq[qh], KC[kt],     \
                                                          z, 0, 0, 0);        \
        float e0 = __builtin_exp2f(s[0]);                                     \
        float e1 = __builtin_exp2f(s[1]);                                     \
        float e2 = __builtin_exp2f(s[2]);                                     \
        float e3 = __builtin_exp2f(s[3]);                                     \
        Lp[qh][0] += e0; Lp[qh][1] += e1;                                     \
        Lp[qh][2] += e2; Lp[qh][3] += e3;                                     \
        unsigned int pk0, pk1;                                                \
        asm("v_cvt_pk_bf16_f32 %0, %1, %2" : "=v"(pk0) : "v"(e0), "v"(e1));   \
        asm("v_cvt_pk_bf16_f32 %0, %1, %2" : "=v"(pk1) : "v"(e2), "v"(e3));   \
        const int rb = (qh * 16 + 4 * g) * 72 + kt * 16 + l15;                \
        PLw[rb]       = (unsigned short)pk0;                                  \
        PLw[rb + 72]  = (unsigned short)(pk0 >> 16);                          \
        PLw[rb + 144] = (unsigned short)pk1;                                  \
        PLw[rb + 216] = (unsigned short)(pk1 >> 16);                          \
      }                                                                       \
    }                                                                         \
    const int mn = kv0 + (((T) + 1 < 8 ? (T) + 1 : 0) << 6);                  \
    _Pragma("unroll") for (int kt = 0; kt < 4; ++kt) {                        \
      KN[kt] = short8{};                                                      \
      if (g < 2)                                                              \
        KN[kt] = *(const short8*)&kbase[(size_t)(mn + kt * 16 + l15) * 16 +   \
                                        g * 8];                               \
    }                                                                         \
    short8 pa0[2];                                                            \
    _Pragma("unroll") for (int ch = 0; ch < 2; ++ch)                          \
      pa0[ch] = *(const short8*)&PLw[l15 * 72 + ch * 32 + g * 8];             \
    __builtin_amdgcn_s_setprio(1);                                            \
    _Pragma("unroll") for (int ch = 0; ch < 2; ++ch)                          \
      _Pragma("unroll") for (int ct = 0; ct < 8; ++ct)                        \
        acc[ct] = __builtin_amdgcn_mfma_f32_16x16x32_bf16(                    \
            pa0[ch], vf[ct * 2 + ch], acc[ct], 0, 0, 0);                      \
    __builtin_amdgcn_s_setprio(0);                                            \
    short8 pa1[2];                                                            \
    _Pragma("unroll") for (int ch = 0; ch < 2; ++ch)                          \
      pa1[ch] = *(const short8*)&PLw[(16 + l15) * 72 + ch * 32 + g * 8];      \
    __builtin_amdgcn_s_setprio(1);                                            \
    _Pragma("unroll") for (int ch = 0; ch < 2; ++ch)                          \
      _Pragma("unroll") for (int ct = 0; ct < 8; ++ct)                        \
        acc[8 + ct] = __builtin_amdgcn_mfma_f32_16x16x32_bf16(                \
            pa1[ch], vf[ct * 2 + ch], acc[8 + ct], 0, 0, 0);                  \
    __builtin_amdgcn_s_setprio(0);                                            \
  }

  for (int tt = 0; tt < 4; ++tt) {
    SA_ITER(tt * 2, kfa, kfb);
    SA_ITER(tt * 2 + 1, kfb, kfa);
  }
#undef SA_ITER

  // intra-wave L reduce over the 16 key-columns
#pragma unroll
  for (int qh = 0; qh < 2; ++qh)
#pragma unroll
    for (int r = 0; r < 4; ++r) {
      float v = Lp[qh][r];
      v += __shfl_xor(v, 1);
      v += __shfl_xor(v, 2);
      v += __shfl_xor(v, 4);
      v += __shfl_xor(v, 8);
      Lp[qh][r] = v;
    }

  // cross-wave tree reduce: 8 -> 4 -> 2 -> 1 (XOR-swizzled 256B rows)
  const int rowb = lane * 256;
  const int sw = (l15) << 4;

#define ACC_STORE(i)                                                        \
  {                                                                         \
    char* base = (char*)smem + (i) * 16384 + rowb;                          \
    _Pragma("unroll") for (int j = 0; j < 16; ++j)                          \
        *(f32x4*)(base + ((j * 16) ^ sw)) = acc[j];                         \
    if (l15 == 0) {                                                         \
      _Pragma("unroll") for (int qh = 0; qh < 2; ++qh)                      \
          _Pragma("unroll") for (int r = 0; r < 4; ++r)                     \
              LDp[(i) * 32 + qh * 16 + 4 * g + r] = Lp[qh][r];              \
    }                                                                       \
  }
#define ACC_ADD(i)                                                          \
  {                                                                         \
    char* base = (char*)smem + (i) * 16384 + rowb;                          \
    _Pragma("unroll") for (int j = 0; j < 16; ++j)                          \
        acc[j] += *(const f32x4*)(base + ((j * 16) ^ sw));                  \
    _Pragma("unroll") for (int qh = 0; qh < 2; ++qh)                        \
        _Pragma("unroll") for (int r = 0; r < 4; ++r)                       \
            Lp[qh][r] += LDp[(i) * 32 + qh * 16 + 4 * g + r];               \
  }

  __syncthreads();
  if (w >= 4) ACC_STORE(w - 4);
  __syncthreads();
  if (w < 4) ACC_ADD(w);
  __syncthreads();
  if (w == 2 || w == 3) ACC_STORE(w - 2);
  __syncthreads();
  if (w < 2) ACC_ADD(w);
  __syncthreads();
  if (w == 1) ACC_STORE(0);
  __syncthreads();

  if (w == 0) {
    ACC_ADD(0);
    const float ga = gamma[0];
    float inv[2][4];
#pragma unroll
    for (int qh = 0; qh < 2; ++qh)
#pragma unroll
      for (int r = 0; r < 4; ++r) inv[qh][r] = 1.0f / Lp[qh][r];

    const float* xb = x + (size_t)b * CDIM * NTOK;
    float* ob = out + (size_t)b * CDIM * NTOK;
#pragma unroll
    for (int qh = 0; qh < 2; ++qh)
#pragma unroll
      for (int ct = 0; ct < 8; ++ct) {
        int c = ct * 16 + l15;
        size_t idx = (size_t)c * NTOK + q0 + qh * 16 + 4 * g;
        f32x4 xv = *(const f32x4*)&xb[idx];
        f32x4 o;
#pragma unroll
        for (int r = 0; r < 4; ++r)
          o[r] = ga * acc[qh * 8 + ct][r] * inv[qh][r] + xv[r];
        *(f32x4*)&ob[idx] = o;
      }
  }
}

extern "C" void kernel_launch(void* const* d_in, const int* in_sizes, int n_in,
                              void* d_out, int out_size, void* d_ws, size_t ws_size,
                              hipStream_t stream) {
  const float* x     = (const float*)d_in[0];
  const float* Wq    = (const float*)d_in[1];
  const float* bq    = (const float*)d_in[2];
  const float* Wk    = (const float*)d_in[3];
  const float* bk    = (const float*)d_in[4];
  const float* Wv    = (const float*)d_in[5];
  const float* bv    = (const float*)d_in[6];
  const float* gamma = (const float*)d_in[7];

  unsigned short* qb = (unsigned short*)d_ws;          // 512 KB
  unsigned short* kb = qb + (size_t)4 * NTOK * 16;     // 512 KB
  unsigned short* vb = kb + (size_t)4 * NTOK * 16;     // 4 MB (tiled layout)
  float* outp = (float*)d_out;

  sa3d_proj<<<dim3(256), dim3(256), 0, stream>>>(x, Wq, bq, Wk, bk, Wv, bv,
                                                 qb, kb, vb);
  sa3d_attn<<<dim3(512), dim3(512), 0, stream>>>(qb, kb, vb, x, gamma, outp);
}

// Round 8
// 69.667 us; speedup vs baseline: 2.0580x; 1.4870x over previous
//
#include <hip/hip_runtime.h>

// SelfAttention3D: B=4, C=128, N=16^3=4096, Cqk=16.
// R12: same-work/2x-occupancy transform of R5. 512 blocks x 512 threads,
// but wave (kg,cg) = key-quarter (1024 keys) x channel-half (64 ch):
//   acc[8]=32 AGPR, vf[8]=32, kf[2]=8, aq 8 -> combined ~112 <= 128
//   -> 4 waves/SIMD -> 2 blocks/CU = 16 waves/CU (R5 was ~188 regs ->
//   2 waves/SIMD = 8 waves/CU; CSV VGPR_Count excludes AGPRs).
// P for each kg-tile is produced COOPERATIVELY (each cg wave does its 2
// key-columns) into kg-shared double-buffered LDS P; one barrier/tile;
// consumed by both cg waves -> no duplicated QK/exp. Total MFMA, exp,
// V-bytes identical to R5. LDS 37.9KB (2 blocks fit). Keeps: contiguous
// 16KB V tiles, exp2 w/ log2e folded into Q, cvt_pk packing, setprio on PV,
// XCD batch pinning.

typedef __attribute__((ext_vector_type(8))) short short8;
typedef __attribute__((ext_vector_type(4))) float f32x4;

#define NTOK 4096
#define CDIM 128
#define L2E 1.44269504088896340736f

__device__ __forceinline__ unsigned short f2bf(float f) {
  unsigned int u = __float_as_uint(f);
  return (unsigned short)((u + 0x7fffu + ((u >> 16) & 1u)) >> 16);
}

// ---------------------------------------------------------------------------
// Projection (unchanged from R11, harness-verified): q,k,v channel-GEMMs.
// qb,kb: [B][N][16] row per token. Q pre-scaled by log2(e).
// vb tiled: elem(b,c,m) = b*524288 + (m>>6)*8192
//           + ((c>>4)*2 + ((m>>5)&1))*512 + ((m>>3)&3)*128 + (c&15)*8 + (m&7)
// ---------------------------------------------------------------------------
__global__ __launch_bounds__(256) void sa3d_proj(
    const float* __restrict__ x,
    const float* __restrict__ Wq, const float* __restrict__ bq,
    const float* __restrict__ Wk, const float* __restrict__ bk,
    const float* __restrict__ Wv, const float* __restrict__ bv,
    unsigned short* __restrict__ qb, unsigned short* __restrict__ kb,
    unsigned short* __restrict__ vb)
{
  __shared__ unsigned short Wl[160 * 136];
  __shared__ unsigned short xT[64 * 136];
  const int tid = threadIdx.x;
  const int b = (blockIdx.x & 7) >> 1;
  const int nt = ((blockIdx.x >> 3) << 1) | (blockIdx.x & 1);  // [0,64)
  const int n0 = nt << 6;

  for (int i = 0; i < 80; ++i) {
    int idx = i * 256 + tid;
    int o = idx >> 7, c = idx & 127;
    float wv;
    if (o < 16)      wv = Wq[o * 128 + c] * L2E;   // fold log2e into Q
    else if (o < 32) wv = Wk[(o - 16) * 128 + c];
    else             wv = Wv[(o - 32) * 128 + c];
    Wl[o * 136 + c] = f2bf(wv);
  }
  {
    int nn = tid & 63, cg = tid >> 6;
    const float* xp = x + (size_t)b * CDIM * NTOK + n0 + nn;
    for (int cp = 0; cp < 16; ++cp) {
      int c = cg * 32 + cp * 2;
      float v0 = xp[(size_t)c * NTOK];
      float v1 = xp[(size_t)(c + 1) * NTOK];
      *(unsigned int*)&xT[nn * 136 + c] =
          (unsigned int)f2bf(v0) | ((unsigned int)f2bf(v1) << 16);
    }
  }
  __syncthreads();

  const int w = tid >> 6, lane = tid & 63;
  const int l15 = lane & 15, g = lane >> 4;

  short8 bfr[4];
#pragma unroll
  for (int ks = 0; ks < 4; ++ks)
    bfr[ks] = *(const short8*)&xT[(w * 16 + l15) * 136 + ks * 32 + g * 8];

  const int n = n0 + w * 16 + l15;
#pragma unroll
  for (int ot = 0; ot < 10; ++ot) {
    f32x4 acc = {};
#pragma unroll
    for (int ks = 0; ks < 4; ++ks) {
      short8 af = *(const short8*)&Wl[(ot * 16 + l15) * 136 + ks * 32 + g * 8];
      acc = __builtin_amdgcn_mfma_f32_16x16x32_bf16(af, bfr[ks], acc, 0, 0, 0);
    }
    int ob = ot * 16 + 4 * g;
    if (ot == 0) {
      unsigned int p0 = (unsigned int)f2bf(acc[0] + bq[ob] * L2E) |
                        ((unsigned int)f2bf(acc[1] + bq[ob + 1] * L2E) << 16);
      unsigned int p1 = (unsigned int)f2bf(acc[2] + bq[ob + 2] * L2E) |
                        ((unsigned int)f2bf(acc[3] + bq[ob + 3] * L2E) << 16);
      unsigned int* d = (unsigned int*)&qb[((size_t)b * NTOK + n) * 16 + ob];
      d[0] = p0; d[1] = p1;
    } else if (ot == 1) {
      int o2 = ob - 16;
      unsigned int p0 = (unsigned int)f2bf(acc[0] + bk[o2]) |
                        ((unsigned int)f2bf(acc[1] + bk[o2 + 1]) << 16);
      unsigned int p1 = (unsigned int)f2bf(acc[2] + bk[o2 + 2]) |
                        ((unsigned int)f2bf(acc[3] + bk[o2 + 3]) << 16);
      unsigned int* d = (unsigned int*)&kb[((size_t)b * NTOK + n) * 16 + o2];
      d[0] = p0; d[1] = p1;
    } else {
#pragma unroll
      for (int r = 0; r < 4; ++r) {
        int o = ob + r - 32;  // channel c in [0,128)
        size_t eidx = (size_t)(n >> 6) * 8192 +
                      (size_t)((o >> 4) * 2 + ((n >> 5) & 1)) * 512 +
                      (size_t)((n >> 3) & 3) * 128 + (o & 15) * 8 + (n & 7);
        vb[(size_t)b * (CDIM * NTOK) + eidx] = f2bf(acc[r] + bv[o]);
      }
    }
  }
}

// ---------------------------------------------------------------------------
// Flash attention. 512 blocks x 512 threads. Block: batch b=(bid&7)>>1,
// 32 queries. Wave w: kg=w>>1 (keys [kg*1024,+1024) = 16 tiles of 64),
// cg=w&1 (channels [cg*64,+64)). Per tile t:
//   pa0 read P(t) (written iter t-1) -> 8 V(t) loads -> cooperative
//   produce P(t+1) (this wave's 2 key-cols: 4 QK MFMA + 16 exp2 + cvt_pk
//   -> kg-shared LDS buf (t+1)&1) -> kf <- K(t+2) -> PV qh0 -> pa1 ->
//   PV qh1 -> barrier.
// End: decoupled L slots (8x32 f32 in LDS, summed by epilogue waves) +
// 2-step acc tree (kg-merge per cg); waves 0,1 do the epilogue (64 ch each).
// ---------------------------------------------------------------------------
__global__ __launch_bounds__(512, 2) void sa3d_attn(
    const unsigned short* __restrict__ qb, const unsigned short* __restrict__ kb,
    const unsigned short* __restrict__ vb,
    const float* __restrict__ x, const float* __restrict__ gamma,
    float* __restrict__ out)
{
  // LDS: [0,36864): 4 kg x 2 bufs x (32 rows x 72 shorts = 4608 B)
  //      [0,32768): 4 acc-reduce slots of 8 KB (reused after loop)
  //      [36864,37888): L slots, 8 waves x 32 floats
  __shared__ __align__(16) unsigned char smem[37888];

  const int tid = threadIdx.x;
  const int w = tid >> 6, lane = tid & 63;
  const int l15 = lane & 15, g = lane >> 4;
  const int kg = w >> 1, cg = w & 1;
  const int b = (blockIdx.x & 7) >> 1;
  const int qt = ((blockIdx.x >> 3) << 1) | (blockIdx.x & 1);  // [0,128)
  const int q0 = qt << 5;

  unsigned short* PLk = (unsigned short*)smem + kg * 4608;  // 2 bufs x 2304
  float* LDp = (float*)(smem + 36864);

  const unsigned short* qbase = qb + (size_t)b * NTOK * 16;
  const unsigned short* kbase = kb + (size_t)b * NTOK * 16;
  const unsigned short* vbase = vb + (size_t)b * CDIM * NTOK;

  short8 aq[2] = {short8{}, short8{}};
#pragma unroll
  for (int qh = 0; qh < 2; ++qh)
    if (g < 2)
      aq[qh] = *(const short8*)&qbase[(size_t)(q0 + qh * 16 + l15) * 16 + g * 8];

  f32x4 acc[8];  // [qh*4 + ctl]
#pragma unroll
  for (int i = 0; i < 8; ++i) acc[i] = (f32x4){};
  float Lp[2][4] = {{0.f, 0.f, 0.f, 0.f}, {0.f, 0.f, 0.f, 0.f}};

  const int kv0 = kg << 10;                     // 1024 keys per kg
  const int kcolb = cg * 32 + l15;              // + j*16 -> this wave's cols
  const int voff = cg * 4096 + g * 128 + l15 * 8;
  const unsigned short* vtile = vbase + (size_t)kg * 16 * 8192;

  short8 kf[2];  // this wave's 2 key-column K fragments, reloaded per tile

#define LOADK(TT)                                                             \
  {                                                                           \
    _Pragma("unroll") for (int j = 0; j < 2; ++j) {                           \
      kf[j] = short8{};                                                       \
      if (g < 2)                                                              \
        kf[j] = *(const short8*)&kbase[                                       \
            (size_t)(kv0 + ((TT) << 6) + kcolb + j * 16) * 16 + g * 8];       \
    }                                                                         \
  }

  // Cooperative produce of P(TN) into kg-shared buf TN&1: this wave covers
  // key-cols cg*32..cg*32+31 (j=0,1): QK -> exp2 -> cvt_pk -> 4 b16 writes.
#define SA_PRODUCE(TN)                                                        \
  {                                                                           \
    const int pbn = ((TN) & 1) * 2304;                                        \
    _Pragma("unroll") for (int j = 0; j < 2; ++j) {                           \
      _Pragma("unroll") for (int qh = 0; qh < 2; ++qh) {                      \
        f32x4 z = {};                                                         \
        f32x4 s = __builtin_amdgcn_mfma_f32_16x16x32_bf16(aq[qh], kf[j],      \
                                                          z, 0, 0, 0);        \
        float e0 = __builtin_exp2f(s[0]);                                     \
        float e1 = __builtin_exp2f(s[1]);                                     \
        float e2 = __builtin_exp2f(s[2]);                                     \
        float e3 = __builtin_exp2f(s[3]);                                     \
        Lp[qh][0] += e0; Lp[qh][1] += e1;                                     \
        Lp[qh][2] += e2; Lp[qh][3] += e3;                                     \
        unsigned int pk0, pk1;                                                \
        asm("v_cvt_pk_bf16_f32 %0, %1, %2" : "=v"(pk0) : "v"(e0), "v"(e1));   \
        asm("v_cvt_pk_bf16_f32 %0, %1, %2" : "=v"(pk1) : "v"(e2), "v"(e3));   \
        const int rb = pbn + (qh * 16 + 4 * g) * 72 + kcolb + j * 16;         \
        PLk[rb]       = (unsigned short)pk0;                                  \
        PLk[rb + 72]  = (unsigned short)(pk0 >> 16);                          \
        PLk[rb + 144] = (unsigned short)pk1;                                  \
        PLk[rb + 216] = (unsigned short)(pk1 >> 16);                          \
      }                                                                       \
    }                                                                         \
  }

  // Iter T: pa0(T) -> V(T) -> produce P(T+1) (if PROD) -> kf<-K(T+2)
  // (if PREF) -> PV qh0 -> pa1 -> PV qh1 -> barrier.
#define SA_ITER(T, PROD, PREF)                                                \
  {                                                                           \
    const int pbo = ((T) & 1) * 2304;                                         \
    short8 pa0[2];                                                            \
    _Pragma("unroll") for (int ch = 0; ch < 2; ++ch)                          \
      pa0[ch] = *(const short8*)&PLk[pbo + l15 * 72 + ch * 32 + g * 8];       \
    short8 vf[8];                                                             \
    {                                                                         \
      const unsigned short* vt = vtile + (size_t)(T) * 8192;                  \
      _Pragma("unroll") for (int f = 0; f < 8; ++f)                           \
        vf[f] = *(const short8*)&vt[f * 512 + voff];                          \
    }                                                                         \
    if (PROD) SA_PRODUCE((T) + 1);                                            \
    if (PREF) LOADK((T) + 2);                                                 \
    __builtin_amdgcn_s_setprio(1);                                            \
    _Pragma("unroll") for (int ctl = 0; ctl < 4; ++ctl)                       \
      _Pragma("unroll") for (int ch = 0; ch < 2; ++ch)                        \
        acc[ctl] = __builtin_amdgcn_mfma_f32_16x16x32_bf16(                   \
            pa0[ch], vf[ctl * 2 + ch], acc[ctl], 0, 0, 0);                    \
    __builtin_amdgcn_s_setprio(0);                                            \
    short8 pa1[2];                                                            \
    _Pragma("unroll") for (int ch = 0; ch < 2; ++ch)                          \
      pa1[ch] = *(const short8*)&PLk[pbo + (16 + l15) * 72 + ch * 32 + g * 8];\
    __builtin_amdgcn_s_setprio(1);                                            \
    _Pragma("unroll") for (int ctl = 0; ctl < 4; ++ctl)                       \
      _Pragma("unroll") for (int ch = 0; ch < 2; ++ch)                        \
        acc[4 + ctl] = __builtin_amdgcn_mfma_f32_16x16x32_bf16(               \
            pa1[ch], vf[ctl * 2 + ch], acc[4 + ctl], 0, 0, 0);                \
    __builtin_amdgcn_s_setprio(0);                                            \
    __syncthreads();                                                          \
  }

  // prologue: K(0), P(0)->buf0, K(1), barrier
  LOADK(0);
  SA_PRODUCE(0);
  LOADK(1);
  __syncthreads();

  for (int tt = 0; tt < 7; ++tt) {
    SA_ITER(2 * tt, 1, 1);
    SA_ITER(2 * tt + 1, 1, 1);
  }
  SA_ITER(14, 1, 0);
  SA_ITER(15, 0, 0);
#undef SA_PRODUCE
#undef SA_ITER
#undef LOADK

  // intra-wave L reduce over the 16 key-columns per l15 group
#pragma unroll
  for (int qh = 0; qh < 2; ++qh)
#pragma unroll
    for (int r = 0; r < 4; ++r) {
      float v = Lp[qh][r];
      v += __shfl_xor(v, 1);
      v += __shfl_xor(v, 2);
      v += __shfl_xor(v, 4);
      v += __shfl_xor(v, 8);
      Lp[qh][r] = v;
    }
  // decoupled per-wave L slot (summed by epilogue waves over all 8)
  if (l15 == 0) {
#pragma unroll
    for (int qh = 0; qh < 2; ++qh)
#pragma unroll
      for (int r = 0; r < 4; ++r)
        LDp[w * 32 + qh * 16 + 4 * g + r] = Lp[qh][r];
  }
  __syncthreads();

  // acc tree: kg-merge within cg. slots: s=w-4 (kg2/3), then s=w-2 (kg1).
  const int rowb = lane * 128;
  const int sw = (l15 & 7) << 4;

#define ACC_STORE(i)                                                        \
  {                                                                         \
    char* base = (char*)smem + (i) * 8192 + rowb;                           \
    _Pragma("unroll") for (int j = 0; j < 8; ++j)                           \
        *(f32x4*)(base + ((j * 16) ^ sw)) = acc[j];                         \
  }
#define ACC_ADD(i)                                                          \
  {                                                                         \
    char* base = (char*)smem + (i) * 8192 + rowb;                           \
    _Pragma("unroll") for (int j = 0; j < 8; ++j)                           \
        acc[j] += *(const f32x4*)(base + ((j * 16) ^ sw));                  \
  }

  if (w >= 4) ACC_STORE(w - 4);
  __syncthreads();
  if (w < 4) ACC_ADD(w);
  __syncthreads();
  if (w == 2 || w == 3) ACC_STORE(w - 2);
  __syncthreads();

  if (w < 2) {
    ACC_ADD(w);
    // full L: sum all 8 wave slots
    float Lf[2][4] = {{0.f, 0.f, 0.f, 0.f}, {0.f, 0.f, 0.f, 0.f}};
#pragma unroll
    for (int w8 = 0; w8 < 8; ++w8)
#pragma unroll
      for (int qh = 0; qh < 2; ++qh)
#pragma unroll
        for (int r = 0; r < 4; ++r)
          Lf[qh][r] += LDp[w8 * 32 + qh * 16 + 4 * g + r];
    const float ga = gamma[0];
    float inv[2][4];
#pragma unroll
    for (int qh = 0; qh < 2; ++qh)
#pragma unroll
      for (int r = 0; r < 4; ++r) inv[qh][r] = 1.0f / Lf[qh][r];

    const float* xb = x + (size_t)b * CDIM * NTOK;
    float* ob = out + (size_t)b * CDIM * NTOK;
#pragma unroll
    for (int qh = 0; qh < 2; ++qh)
#pragma unroll
      for (int ctl = 0; ctl < 4; ++ctl) {
        int c = w * 64 + ctl * 16 + l15;   // cg == w for w in {0,1}
        size_t idx = (size_t)c * NTOK + q0 + qh * 16 + 4 * g;
        f32x4 xv = *(const f32x4*)&xb[idx];
        f32x4 o;
#pragma unroll
        for (int r = 0; r < 4; ++r)
          o[r] = ga * acc[qh * 4 + ctl][r] * inv[qh][r] + xv[r];
        *(f32x4*)&ob[idx] = o;
      }
  }
}

extern "C" void kernel_launch(void* const* d_in, const int* in_sizes, int n_in,
                              void* d_out, int out_size, void* d_ws, size_t ws_size,
                              hipStream_t stream) {
  const float* x     = (const float*)d_in[0];
  const float* Wq    = (const float*)d_in[1];
  const float* bq    = (const float*)d_in[2];
  const float* Wk    = (const float*)d_in[3];
  const float* bk    = (const float*)d_in[4];
  const float* Wv    = (const float*)d_in[5];
  const float* bv    = (const float*)d_in[6];
  const float* gamma = (const float*)d_in[7];

  unsigned short* qb = (unsigned short*)d_ws;          // 512 KB
  unsigned short* kb = qb + (size_t)4 * NTOK * 16;     // 512 KB
  unsigned short* vb = kb + (size_t)4 * NTOK * 16;     // 4 MB (tiled layout)
  float* outp = (float*)d_out;

  sa3d_proj<<<dim3(256), dim3(256), 0, stream>>>(x, Wq, bq, Wk, bk, Wv, bv,
                                                 qb, kb, vb);
  sa3d_attn<<<dim3(512), dim3(512), 0, stream>>>(qb, kb, vb, x, gamma, outp);
}